// Round 8
// baseline (430.564 us; speedup 1.0000x reference)
//
#include <hip/hip_runtime.h>
#include <math.h>

// Problem constants
#define BATCH   32768
#define DIMX    64
#define FEATD   128
#define IN1     192      // FEATDIM + DIM
#define WIDTH   1536
#define ONC     896      // DIM * (3K-1)

// Tiling
#define NT      512      // 8 waves
#define H_LD    1544     // h row stride in bf16 elems (1536 + 8 pad)
#define IN_LD   200      // input row stride in bf16 elems (192 + 8 pad)
#define O_LD    904      // obuf row stride in f32 (896 + 8 pad)

typedef __attribute__((ext_vector_type(8))) short short8;
typedef __attribute__((ext_vector_type(4))) float f32x4;

#define MFMA_BF16(a,b,c) __builtin_amdgcn_mfma_f32_16x16x32_bf16((a),(b),(c),0,0,0)
#define TS 4096   // B elems between a wave's consecutive n-tiles (8 tiles * 512)

__device__ __forceinline__ unsigned short f2bf(float f) {
  unsigned u = __builtin_bit_cast(unsigned, f);
  u += 0x7fffu + ((u >> 16) & 1u);            // round-to-nearest-even
  return (unsigned short)(u >> 16);
}
__device__ __forceinline__ float wave_sum64(float v) {
  #pragma unroll
  for (int o = 32; o > 0; o >>= 1) v += __shfl_xor(v, o, 64);
  return v;
}
__device__ __forceinline__ float softplusf(float t) {
  return fmaxf(t, 0.f) + log1pf(expf(-fabsf(t)));
}

// ---------------------------------------------------------------------------
// Merged pack: all three weights in ONE launch (unchanged from R7).
// ---------------------------------------------------------------------------
__global__ __launch_bounds__(256) void pack_all(
    const float* __restrict__ w1, const float* __restrict__ w2,
    const float* __restrict__ w3,
    unsigned short* __restrict__ w1p, unsigned short* __restrict__ w2p,
    unsigned short* __restrict__ w3p) {
  const int wv = (blockIdx.x * 256 + threadIdx.x) >> 6;
  const int lane = threadIdx.x & 63;
  const float* W; unsigned short* out; int N, K, id;
  if (wv < 576)       { W = w1; out = w1p; N = WIDTH; K = IN1;   id = wv; }
  else if (wv < 5184) { W = w2; out = w2p; N = WIDTH; K = WIDTH; id = wv - 576; }
  else if (wv < 7872) { W = w3; out = w3p; N = ONC;   K = WIDTH; id = wv - 5184; }
  else return;
  const int nbt = N / 16;
  const int kb = id / nbt, nb = id - kb * nbt;
  const int n = nb * 16 + (lane & 15);
  const int k = kb * 32 + (lane >> 4) * 8;
  const float* src = W + (size_t)n * K + k;
  const float4 v0 = *(const float4*)src;
  const float4 v1 = *(const float4*)(src + 4);
  short8 o;
  o[0] = (short)f2bf(v0.x); o[1] = (short)f2bf(v0.y);
  o[2] = (short)f2bf(v0.z); o[3] = (short)f2bf(v0.w);
  o[4] = (short)f2bf(v1.x); o[5] = (short)f2bf(v1.y);
  o[6] = (short)f2bf(v1.z); o[7] = (short)f2bf(v1.w);
  *(short8*)(out + ((size_t)id * 64 + lane) * 8) = o;
}

// ---------------------------------------------------------------------------
// Depth-4 pipelined B-stream with 1:N load<->MFMA interleave (AITER pattern):
// each B slot is refilled immediately after the MFMAs that consume it, inside
// the MFMA cluster, instead of trailing the whole cluster. WAR-safe in-order.
// ---------------------------------------------------------------------------
template<int RBT, int NTILE, int ASTR, int NKB>
__device__ __forceinline__ void stream4(
    const unsigned short* __restrict__ pB, size_t kstr,
    const unsigned short* hbase, int ald,
    f32x4* acc, int l15, int l4)
{
  const unsigned short* pA[RBT];
  #pragma unroll
  for (int rb = 0; rb < RBT; ++rb) pA[rb] = hbase + (size_t)(rb * 16 + l15) * ald + l4 * 8;

  short8 B0[NTILE], B1[NTILE], B2[NTILE], B3[NTILE];
  #pragma unroll
  for (int nb = 0; nb < NTILE; ++nb) B0[nb] = *(const short8*)(pB + nb * TS);
  pB += kstr;
  #pragma unroll
  for (int nb = 0; nb < NTILE; ++nb) B1[nb] = *(const short8*)(pB + nb * TS);
  pB += kstr;
  #pragma unroll
  for (int nb = 0; nb < NTILE; ++nb) B2[nb] = *(const short8*)(pB + nb * TS);
  pB += kstr;
  #pragma unroll
  for (int nb = 0; nb < NTILE; ++nb) B3[nb] = *(const short8*)(pB + nb * TS);
  pB += kstr;

  short8 aE[RBT], aO[RBT];
  #pragma unroll
  for (int rb = 0; rb < RBT; ++rb) aE[rb] = *(const short8*)(pA[rb]);

  #pragma unroll 1
  for (int it = 0; it < NKB / 4 - 1; ++it) {
    const int kb = it * 4;
    // ph0: consume (aE,B0)=kb; refill B0<-kb+4 interleaved; prefetch aO=A[kb+1]
    #pragma unroll
    for (int rb = 0; rb < RBT; ++rb) aO[rb] = *(const short8*)(pA[rb] + (kb + 1) * 32);
    __builtin_amdgcn_s_setprio(1);
    #pragma unroll
    for (int nb = 0; nb < NTILE; ++nb) {
      #pragma unroll
      for (int rb = 0; rb < RBT; ++rb)
        acc[rb * ASTR + nb] = MFMA_BF16(aE[rb], B0[nb], acc[rb * ASTR + nb]);
      B0[nb] = *(const short8*)(pB + nb * TS);
    }
    __builtin_amdgcn_s_setprio(0);
    pB += kstr;
    // ph1
    #pragma unroll
    for (int rb = 0; rb < RBT; ++rb) aE[rb] = *(const short8*)(pA[rb] + (kb + 2) * 32);
    __builtin_amdgcn_s_setprio(1);
    #pragma unroll
    for (int nb = 0; nb < NTILE; ++nb) {
      #pragma unroll
      for (int rb = 0; rb < RBT; ++rb)
        acc[rb * ASTR + nb] = MFMA_BF16(aO[rb], B1[nb], acc[rb * ASTR + nb]);
      B1[nb] = *(const short8*)(pB + nb * TS);
    }
    __builtin_amdgcn_s_setprio(0);
    pB += kstr;
    // ph2
    #pragma unroll
    for (int rb = 0; rb < RBT; ++rb) aO[rb] = *(const short8*)(pA[rb] + (kb + 3) * 32);
    __builtin_amdgcn_s_setprio(1);
    #pragma unroll
    for (int nb = 0; nb < NTILE; ++nb) {
      #pragma unroll
      for (int rb = 0; rb < RBT; ++rb)
        acc[rb * ASTR + nb] = MFMA_BF16(aE[rb], B2[nb], acc[rb * ASTR + nb]);
      B2[nb] = *(const short8*)(pB + nb * TS);
    }
    __builtin_amdgcn_s_setprio(0);
    pB += kstr;
    // ph3
    #pragma unroll
    for (int rb = 0; rb < RBT; ++rb) aE[rb] = *(const short8*)(pA[rb] + (kb + 4) * 32);
    __builtin_amdgcn_s_setprio(1);
    #pragma unroll
    for (int nb = 0; nb < NTILE; ++nb) {
      #pragma unroll
      for (int rb = 0; rb < RBT; ++rb)
        acc[rb * ASTR + nb] = MFMA_BF16(aO[rb], B3[nb], acc[rb * ASTR + nb]);
      B3[nb] = *(const short8*)(pB + nb * TS);
    }
    __builtin_amdgcn_s_setprio(0);
    pB += kstr;
  }
  // epilogue: kb = NKB-4 .. NKB-1 (no refills)
  {
    #pragma unroll
    for (int rb = 0; rb < RBT; ++rb) aO[rb] = *(const short8*)(pA[rb] + (NKB - 3) * 32);
    __builtin_amdgcn_s_setprio(1);
    #pragma unroll
    for (int nb = 0; nb < NTILE; ++nb)
      #pragma unroll
      for (int rb = 0; rb < RBT; ++rb)
        acc[rb * ASTR + nb] = MFMA_BF16(aE[rb], B0[nb], acc[rb * ASTR + nb]);
    #pragma unroll
    for (int rb = 0; rb < RBT; ++rb) aE[rb] = *(const short8*)(pA[rb] + (NKB - 2) * 32);
    #pragma unroll
    for (int nb = 0; nb < NTILE; ++nb)
      #pragma unroll
      for (int rb = 0; rb < RBT; ++rb)
        acc[rb * ASTR + nb] = MFMA_BF16(aO[rb], B1[nb], acc[rb * ASTR + nb]);
    #pragma unroll
    for (int rb = 0; rb < RBT; ++rb) aO[rb] = *(const short8*)(pA[rb] + (NKB - 1) * 32);
    #pragma unroll
    for (int nb = 0; nb < NTILE; ++nb)
      #pragma unroll
      for (int rb = 0; rb < RBT; ++rb)
        acc[rb * ASTR + nb] = MFMA_BF16(aE[rb], B2[nb], acc[rb * ASTR + nb]);
    #pragma unroll
    for (int nb = 0; nb < NTILE; ++nb)
      #pragma unroll
      for (int rb = 0; rb < RBT; ++rb)
        acc[rb * ASTR + nb] = MFMA_BF16(aO[rb], B3[nb], acc[rb * ASTR + nb]);
    __builtin_amdgcn_s_setprio(0);
  }
}

// ---------------------------------------------------------------------------
// Runtime-bound depth-3 stream for AR tails (nkb >= 3), interleaved refills.
// ---------------------------------------------------------------------------
template<int RBT, int NTILE, int ASTR>
__device__ __forceinline__ void stream_rt3(
    const unsigned short* __restrict__ pB, size_t kstr,
    const unsigned short* hbase, int ald,
    f32x4* acc, int l15, int l4, int nkb)
{
  const unsigned short* pA[RBT];
  #pragma unroll
  for (int rb = 0; rb < RBT; ++rb) pA[rb] = hbase + (size_t)(rb * 16 + l15) * ald + l4 * 8;

  short8 b0[NTILE], b1[NTILE], b2[NTILE], av[RBT];
  #pragma unroll
  for (int nb = 0; nb < NTILE; ++nb) b0[nb] = *(const short8*)(pB + nb * TS);
  pB += kstr;
  #pragma unroll
  for (int nb = 0; nb < NTILE; ++nb) b1[nb] = *(const short8*)(pB + nb * TS);
  pB += kstr;
  #pragma unroll
  for (int nb = 0; nb < NTILE; ++nb) b2[nb] = *(const short8*)(pB + nb * TS);
  pB += kstr;

#define RT_PHASE(BUF, KOFF, REFILL)                                            \
  {                                                                            \
    _Pragma("unroll")                                                          \
    for (int rb = 0; rb < RBT; ++rb) av[rb] = *(const short8*)(pA[rb] + (KOFF) * 32); \
    __builtin_amdgcn_s_setprio(1);                                             \
    _Pragma("unroll")                                                          \
    for (int nb = 0; nb < NTILE; ++nb) {                                       \
      _Pragma("unroll")                                                        \
      for (int rb = 0; rb < RBT; ++rb)                                         \
        acc[rb * ASTR + nb] = MFMA_BF16(av[rb], BUF[nb], acc[rb * ASTR + nb]); \
      if (REFILL) BUF[nb] = *(const short8*)(pB + nb * TS);                    \
    }                                                                          \
    __builtin_amdgcn_s_setprio(0);                                             \
    if (REFILL) pB += kstr;                                                    \
  }

  int k = 0;
  #pragma unroll 1
  for (; k + 6 <= nkb; k += 3) {
    RT_PHASE(b0, k,     true)
    RT_PHASE(b1, k + 1, true)
    RT_PHASE(b2, k + 2, true)
  }
  // remainder: nkb-k in [3,5]
  RT_PHASE(b0, k,     (k + 3 < nkb))
  RT_PHASE(b1, k + 1, (k + 4 < nkb))
  RT_PHASE(b2, k + 2, false)
  k += 3;
  if (k < nkb)     RT_PHASE(b0, k, false)
  if (k + 1 < nkb) RT_PHASE(b1, k + 1, false)
#undef RT_PHASE
}

// ---------------------------------------------------------------------------
// Depth-2 runtime stream (kept for GEMM1's 2-kb tail only).
// ---------------------------------------------------------------------------
template<int RBT, int NTILE, int ASTR>
__device__ __forceinline__ void stream_rt2(
    const unsigned short* __restrict__ pB, size_t kstr,
    const unsigned short* hbase, int ald,
    f32x4* acc, int l15, int l4, int nkb)
{
  if (nkb <= 0) return;
  const unsigned short* pA[RBT];
  #pragma unroll
  for (int rb = 0; rb < RBT; ++rb) pA[rb] = hbase + (size_t)(rb * 16 + l15) * ald + l4 * 8;

  short8 bA[NTILE], bB[NTILE], av[RBT];
  #pragma unroll
  for (int nb = 0; nb < NTILE; ++nb) bA[nb] = *(const short8*)(pB + nb * TS);
  pB += kstr;
  int k = 0;
  #pragma unroll 1
  for (; k + 2 <= nkb; k += 2) {
    #pragma unroll
    for (int nb = 0; nb < NTILE; ++nb) bB[nb] = *(const short8*)(pB + nb * TS);
    pB += kstr;
    #pragma unroll
    for (int rb = 0; rb < RBT; ++rb) av[rb] = *(const short8*)(pA[rb] + k * 32);
    __builtin_amdgcn_s_setprio(1);
    #pragma unroll
    for (int nb = 0; nb < NTILE; ++nb)
      #pragma unroll
      for (int rb = 0; rb < RBT; ++rb)
        acc[rb * ASTR + nb] = MFMA_BF16(av[rb], bA[nb], acc[rb * ASTR + nb]);
    __builtin_amdgcn_s_setprio(0);
    if (k + 2 < nkb) {
      #pragma unroll
      for (int nb = 0; nb < NTILE; ++nb) bA[nb] = *(const short8*)(pB + nb * TS);
    }
    pB += kstr;
    #pragma unroll
    for (int rb = 0; rb < RBT; ++rb) av[rb] = *(const short8*)(pA[rb] + (k + 1) * 32);
    __builtin_amdgcn_s_setprio(1);
    #pragma unroll
    for (int nb = 0; nb < NTILE; ++nb)
      #pragma unroll
      for (int rb = 0; rb < RBT; ++rb)
        acc[rb * ASTR + nb] = MFMA_BF16(av[rb], bB[nb], acc[rb * ASTR + nb]);
    __builtin_amdgcn_s_setprio(0);
  }
  if (k < nkb) {
    #pragma unroll
    for (int rb = 0; rb < RBT; ++rb) av[rb] = *(const short8*)(pA[rb] + k * 32);
    #pragma unroll
    for (int nb = 0; nb < NTILE; ++nb)
      #pragma unroll
      for (int rb = 0; rb < RBT; ++rb)
        acc[rb * ASTR + nb] = MFMA_BF16(av[rb], bA[nb], acc[rb * ASTR + nb]);
  }
}

// ---------------------------------------------------------------------------
// bias + leaky + LayerNorm (unchanged; wave w owns n-tiles {8a+w}).
// ---------------------------------------------------------------------------
template<int RBT>
__device__ __forceinline__ void act_ln(f32x4 (&acc)[RBT][12],
    const float* __restrict__ bias, const float* __restrict__ gam,
    const float* __restrict__ bet,
    unsigned short* hbuf, float* red, float* mstd,
    int t, int w, int l15, int l4)
{
  #pragma unroll
  for (int nb = 0; nb < 12; ++nb) {
    const float bb = bias[nb * 128 + w * 16 + l15];
    #pragma unroll
    for (int rb = 0; rb < RBT; ++rb)
      #pragma unroll
      for (int i = 0; i < 4; ++i) {
        float v = acc[rb][nb][i] + bb;
        acc[rb][nb][i] = v > 0.f ? v : 0.2f * v;
      }
  }
  #pragma unroll
  for (int rb = 0; rb < RBT; ++rb)
    #pragma unroll
    for (int i = 0; i < 4; ++i) {
      float ss = 0.f, qq = 0.f;
      #pragma unroll
      for (int nb = 0; nb < 12; ++nb) {
        const float v = acc[rb][nb][i];
        ss += v; qq += v * v;
      }
      #pragma unroll
      for (int o = 1; o < 16; o <<= 1) { ss += __shfl_xor(ss, o, 64); qq += __shfl_xor(qq, o, 64); }
      if (l15 == 0) {
        const int r = rb * 16 + l4 * 4 + i;
        red[w * 96 + r] = ss;
        red[w * 96 + 48 + r] = qq;
      }
    }
  __syncthreads();
  if (t < 16 * RBT) {
    float ss = 0.f, qq = 0.f;
    #pragma unroll
    for (int w8 = 0; w8 < 8; ++w8) { ss += red[w8 * 96 + t]; qq += red[w8 * 96 + 48 + t]; }
    const float m = ss * (1.f / (float)WIDTH);
    const float v = qq * (1.f / (float)WIDTH) - m * m;
    mstd[t] = m;
    mstd[48 + t] = rsqrtf(fmaxf(v, 0.f) + 1e-5f);
  }
  __syncthreads();
  float mm[RBT][4], rr[RBT][4];
  #pragma unroll
  for (int rb = 0; rb < RBT; ++rb)
    #pragma unroll
    for (int i = 0; i < 4; ++i) {
      const int r = rb * 16 + l4 * 4 + i;
      mm[rb][i] = mstd[r]; rr[rb][i] = mstd[48 + r];
    }
  #pragma unroll
  for (int rb = 0; rb < RBT; ++rb) {
    unsigned short* wp = hbuf + (size_t)(rb * 16 + l4 * 4) * H_LD + w * 16 + l15;
    #pragma unroll
    for (int nb = 0; nb < 12; ++nb) {
      const int col = nb * 128 + w * 16 + l15;
      const float gg = gam[col], ee = bet[col];
      #pragma unroll
      for (int i = 0; i < 4; ++i)
        wp[(size_t)i * H_LD + nb * 128] =
            f2bf((acc[rb][nb][i] - mm[rb][i]) * rr[rb][i] * gg + ee);
    }
  }
  __syncthreads();
}

// ---------------------------------------------------------------------------
// RQS spline (unchanged).
// ---------------------------------------------------------------------------
__device__ __forceinline__ void spline_eval(const float* __restrict__ o, float xv,
                                            float& zret, float& ladd) {
  const float Wv0 = o[0], Wv1 = o[1], Wv2 = o[2], Wv3 = o[3], Wv4 = o[4];
  const float Hv0 = o[5], Hv1 = o[6], Hv2 = o[7], Hv3 = o[8], Hv4 = o[9];
  const float Dv0 = o[10], Dv1 = o[11], Dv2 = o[12], Dv3 = o[13];

  float mw = fmaxf(fmaxf(fmaxf(Wv0, Wv1), fmaxf(Wv2, Wv3)), Wv4);
  float e0 = expf(Wv0 - mw), e1 = expf(Wv1 - mw), e2 = expf(Wv2 - mw),
        e3 = expf(Wv3 - mw), e4 = expf(Wv4 - mw);
  float inv = 0.995f / (e0 + e1 + e2 + e3 + e4);
  const float wd0 = 0.001f + e0 * inv, wd1 = 0.001f + e1 * inv,
              wd2 = 0.001f + e2 * inv, wd3 = 0.001f + e3 * inv;
  const float c1 = wd0, c2 = c1 + wd1, c3 = c2 + wd2, c4 = c3 + wd3;
  const float wi0 = c1, wi1 = c2 - c1, wi2 = c3 - c2, wi3 = c4 - c3, wi4 = 1.f - c4;

  float mh = fmaxf(fmaxf(fmaxf(Hv0, Hv1), fmaxf(Hv2, Hv3)), Hv4);
  float f0 = expf(Hv0 - mh), f1e = expf(Hv1 - mh), f2e = expf(Hv2 - mh),
        f3e = expf(Hv3 - mh), f4e = expf(Hv4 - mh);
  float invh = 0.995f / (f0 + f1e + f2e + f3e + f4e);
  const float hd0 = 0.001f + f0 * invh, hd1 = 0.001f + f1e * invh,
              hd2 = 0.001f + f2e * invh, hd3 = 0.001f + f3e * invh;
  const float g1c = hd0, g2c = g1c + hd1, g3c = g2c + hd2, g4c = g3c + hd3;
  const float hi0 = g1c, hi1 = g2c - g1c, hi2 = g3c - g2c, hi3 = g4c - g3c, hi4 = 1.f - g4c;

  const float dv1 = 0.001f + softplusf(Dv0), dv2 = 0.001f + softplusf(Dv1),
              dv3 = 0.001f + softplusf(Dv2), dv4 = 0.001f + softplusf(Dv3);

  const float s = 1.f / (1.f + expf(-xv));
  const int idx = (int)(s >= c1) + (int)(s >= c2) + (int)(s >= c3) + (int)(s >= c4);

  const float in_cw = idx == 0 ? 0.f : idx == 1 ? c1  : idx == 2 ? c2  : idx == 3 ? c3  : c4;
  const float in_w  = idx == 0 ? wi0 : idx == 1 ? wi1 : idx == 2 ? wi2 : idx == 3 ? wi3 : wi4;
  const float in_h  = idx == 0 ? hi0 : idx == 1 ? hi1 : idx == 2 ? hi2 : idx == 3 ? hi3 : hi4;
  const float in_ch = idx == 0 ? 0.f : idx == 1 ? g1c : idx == 2 ? g2c : idx == 3 ? g3c : g4c;
  const float d0    = idx == 0 ? 1.f : idx == 1 ? dv1 : idx == 2 ? dv2 : idx == 3 ? dv3 : dv4;
  const float d1    = idx == 0 ? dv1 : idx == 1 ? dv2 : idx == 2 ? dv3 : idx == 3 ? dv4 : 1.f;

  const float delta = in_h / in_w;
  const float th  = (s - in_cw) / in_w;
  const float omt = 1.f - th;
  const float t1  = th * omt;
  const float num = in_h * (delta * th * th + d0 * t1);
  const float den = delta + (d0 + d1 - 2.f * delta) * t1;
  float outv = in_ch + num / den;
  const float dnum = delta * delta * (d1 * th * th + 2.f * delta * t1 + d0 * omt * omt);
  const float lad_rqs = logf(dnum) - 2.f * logf(den);
  outv = outv * 0.999998f + 1e-6f;
  const float lo = logf(outv), l1m = logf(1.f - outv);
  const float logds = -softplusf(-xv) - softplusf(xv);
  zret = lo - l1m;
  ladd = logds + lad_rqs - lo - l1m;
}

// ---------------------------------------------------------------------------
// Fused body. Waves 4-7 use a DIFFERENT phase period (4/3-tile groups) than
// waves 0-3 (6/7-tile groups) so the two waves sharing a SIMD drift out of
// stall-lockstep. Per-tile K accumulation order is unchanged -> bit-identical.
// ---------------------------------------------------------------------------
template<int RBT>
__device__ __forceinline__ void body(
    unsigned char* smem,
    const float* __restrict__ x, const float* __restrict__ feat,
    const unsigned short* __restrict__ w1p, const float* __restrict__ b1,
    const float* __restrict__ g1, const float* __restrict__ be1,
    const unsigned short* __restrict__ w2p, const float* __restrict__ b2,
    const float* __restrict__ g2, const float* __restrict__ be2,
    const unsigned short* __restrict__ w3p, const float* __restrict__ b3,
    float* __restrict__ zout, float* __restrict__ ladout, int b0)
{
  constexpr int BMT = 16 * RBT;
  unsigned short* hbuf = (unsigned short*)smem;
  float* red  = (float*)(smem + 48 * H_LD * 2);
  float* mstd = red + 768;

  const int t = threadIdx.x;
  const int lane = t & 63, w = t >> 6;
  const int l15 = lane & 15, l4 = lane >> 4;

  // ---- stage concat([feat, x]) as bf16 ----
  for (int idx = t; idx < BMT * IN1; idx += NT) {
    const int r = idx / IN1, c = idx - r * IN1;
    const int row = b0 + r;
    const float v = (c < FEATD) ? feat[(size_t)row * FEATD + c]
                                : x[(size_t)row * DIMX + (c - FEATD)];
    hbuf[r * IN_LD + c] = f2bf(v);
  }
  __syncthreads();

  const unsigned short* bw1 = w1p + (size_t)w * 512 + lane * 8;
  const unsigned short* bw2 = w2p + (size_t)w * 512 + lane * 8;
  const unsigned short* bw3 = w3p + (size_t)w * 512 + lane * 8;

  // ================= GEMM1 (tiny; no stagger) ================================
  f32x4 acc[RBT][12];
  #pragma unroll
  for (int rb = 0; rb < RBT; ++rb)
    #pragma unroll
    for (int nb = 0; nb < 12; ++nb) acc[rb][nb] = (f32x4){0.f, 0.f, 0.f, 0.f};

  stream4<RBT, 6, 12, 4>(bw1,               (size_t)96 * 512, hbuf, IN_LD, &acc[0][0], l15, l4);
  stream4<RBT, 6, 12, 4>(bw1 + 6 * TS,      (size_t)96 * 512, hbuf, IN_LD, &acc[0][6], l15, l4);
  stream_rt2<RBT, 4, 12>(w1p + ((size_t)4 * 96 + 64 + w) * 512 + lane * 8, (size_t)96 * 512,
                         hbuf + 4 * 32, IN_LD, &acc[0][8], l15, l4, 2);
  act_ln<RBT>(acc, b1, g1, be1, hbuf, red, mstd, t, w, l15, l4);

  // ================= GEMM2: K=1024 dense (staggered periods) + AR tail =======
  #pragma unroll
  for (int rb = 0; rb < RBT; ++rb)
    #pragma unroll
    for (int nb = 0; nb < 12; ++nb) acc[rb][nb] = (f32x4){0.f, 0.f, 0.f, 0.f};

  if (w < 4) {
    stream4<RBT, 6, 12, 32>(bw2,          (size_t)96 * 512, hbuf, H_LD, &acc[0][0], l15, l4);
    stream4<RBT, 6, 12, 32>(bw2 + 6 * TS, (size_t)96 * 512, hbuf, H_LD, &acc[0][6], l15, l4);
  } else {
    stream4<RBT, 4, 12, 32>(bw2,          (size_t)96 * 512, hbuf, H_LD, &acc[0][0], l15, l4);
    stream4<RBT, 4, 12, 32>(bw2 + 4 * TS, (size_t)96 * 512, hbuf, H_LD, &acc[0][4], l15, l4);
    stream4<RBT, 4, 12, 32>(bw2 + 8 * TS, (size_t)96 * 512, hbuf, H_LD, &acc[0][8], l15, l4);
  }
  stream_rt3<RBT, 4, 12>(w2p + ((size_t)32 * 96 + 64 + w) * 512 + lane * 8, (size_t)96 * 512,
                         hbuf + 32 * 32, H_LD, &acc[0][8], l15, l4, (26 + w) >> 1);
  act_ln<RBT>(acc, b2, g2, be2, hbuf, red, mstd, t, w, l15, l4);

  // ================= GEMM3: K=1024 dense (staggered) + 2 AR tails ============
  f32x4 acc3[RBT][7];
  #pragma unroll
  for (int rb = 0; rb < RBT; ++rb)
    #pragma unroll
    for (int nb = 0; nb < 7; ++nb) acc3[rb][nb] = (f32x4){0.f, 0.f, 0.f, 0.f};

  if (w < 4) {
    stream4<RBT, 7, 7, 32>(bw3,           (size_t)56 * 512, hbuf, H_LD, &acc3[0][0], l15, l4);
  } else {
    stream4<RBT, 4, 7, 32>(bw3,           (size_t)56 * 512, hbuf, H_LD, &acc3[0][0], l15, l4);
    stream4<RBT, 3, 7, 32>(bw3 + 4 * TS,  (size_t)56 * 512, hbuf, H_LD, &acc3[0][4], l15, l4);
  }
  {
    const int jmaxA = (16 * (24 + w) + 15) / 14;
    const int jmaxB = (16 * (48 + w) + 15) / 14;
    int nkbA = (8 * jmaxA + 8 + 31) >> 5; if (nkbA > 16) nkbA = 16;
    int nkbB = (8 * jmaxB + 8 + 31) >> 5; if (nkbB > 16) nkbB = 16;
    stream_rt3<RBT, 4, 7>(w3p + ((size_t)32 * 56 + w) * 512 + lane * 8, (size_t)56 * 512,
                          hbuf + 32 * 32, H_LD, &acc3[0][0], l15, l4, nkbA);
    stream_rt3<RBT, 3, 7>(w3p + ((size_t)32 * 56 + 32 + w) * 512 + lane * 8, (size_t)56 * 512,
                          hbuf + 32 * 32, H_LD, &acc3[0][4], l15, l4, nkbB);
  }
  __syncthreads();   // all hbuf A-reads done; obuf may alias hbuf

  // ================= spline via block-shared obuf =============================
  float* obuf = (float*)smem;    // [16][O_LD] f32
  #pragma unroll 1
  for (int rb = 0; rb < RBT; ++rb) {
    #pragma unroll
    for (int a = 0; a < 7; ++a) {
      const int col = (8 * a + w) * 16 + l15;
      const float bb = b3[col];
      #pragma unroll
      for (int i = 0; i < 4; ++i)
        obuf[(size_t)(l4 * 4 + i) * O_LD + col] = acc3[rb][a][i] + bb;
    }
    __syncthreads();
    #pragma unroll 1
    for (int rr = 0; rr < 2; ++rr) {
      const int row = 2 * w + rr;
      const int grow = b0 + rb * 16 + row;
      const float xv = x[(size_t)grow * DIMX + lane];
      float z, lad;
      spline_eval(&obuf[(size_t)row * O_LD + lane * 14], xv, z, lad);
      zout[(size_t)grow * DIMX + lane] = z;
      const float tot = wave_sum64(lad);
      if (lane == 0) ladout[grow] = tot;
    }
    __syncthreads();
  }
}

// ---------------------------------------------------------------------------
// Single fused dispatch: blocks [0,512) -> 48 rows each; [512,768) -> 32 rows.
// ---------------------------------------------------------------------------
__global__ __launch_bounds__(NT, 2) void nsf_fused(
    const float* __restrict__ x, const float* __restrict__ feat,
    const unsigned short* __restrict__ w1p, const float* __restrict__ b1,
    const float* __restrict__ g1, const float* __restrict__ be1,
    const unsigned short* __restrict__ w2p, const float* __restrict__ b2,
    const float* __restrict__ g2, const float* __restrict__ be2,
    const unsigned short* __restrict__ w3p, const float* __restrict__ b3,
    float* __restrict__ zout, float* __restrict__ ladout)
{
  __shared__ __align__(16) unsigned char smem[48 * H_LD * 2 + 768 * 4 + 96 * 4];
  if (blockIdx.x < 512)
    body<3>(smem, x, feat, w1p, b1, g1, be1, w2p, b2, g2, be2, w3p, b3,
            zout, ladout, blockIdx.x * 48);
  else
    body<2>(smem, x, feat, w1p, b1, g1, be1, w2p, b2, g2, be2, w3p, b3,
            zout, ladout, 24576 + (blockIdx.x - 512) * 32);
}

// ---------------------------------------------------------------------------
extern "C" void kernel_launch(void* const* d_in, const int* in_sizes, int n_in,
                              void* d_out, int out_size, void* d_ws, size_t ws_size,
                              hipStream_t stream) {
  const float* x   = (const float*)d_in[0];
  const float* feat= (const float*)d_in[1];
  const float* w1  = (const float*)d_in[2];   // [1536][192]  pre-masked
  const float* b1  = (const float*)d_in[3];
  const float* g1  = (const float*)d_in[4];
  const float* be1 = (const float*)d_in[5];
  const float* w2  = (const float*)d_in[6];   // [1536][1536] pre-masked
  const float* b2  = (const float*)d_in[7];
  const float* g2  = (const float*)d_in[8];
  const float* be2 = (const float*)d_in[9];
  const float* w3  = (const float*)d_in[10];  // [896][1536]  pre-masked
  const float* b3  = (const float*)d_in[11];
  // masks unused: weights arrive pre-masked (mask is 0/1, idempotent).

  unsigned short* w1p = (unsigned short*)d_ws;                 // 576 tiles
  unsigned short* w2p = w1p + (size_t)576 * 512;               // 4608 tiles
  unsigned short* w3p = w2p + (size_t)4608 * 512;              // 2688 tiles

  pack_all<<<1968, 256, 0, stream>>>(w1, w2, w3, w1p, w2p, w3p);

  float* zout   = (float*)d_out;
  float* ladout = zout + (size_t)BATCH * DIMX;
  nsf_fused<<<768, NT, 0, stream>>>(x, feat, w1p, b1, g1, be1,
                                    w2p, b2, g2, be2, w3p, b3,
                                    zout, ladout);
}

// Round 9
// 371.838 us; speedup vs baseline: 1.1579x; 1.1579x over previous
//
#include <hip/hip_runtime.h>
#include <math.h>

// Problem constants
#define BATCH   32768
#define DIMX    64
#define FEATD   128
#define IN1     192      // FEATDIM + DIM
#define WIDTH   1536
#define ONC     896      // DIM * (3K-1)

// Tiling
#define NT      512      // 8 waves
#define H_LD    1544     // h row stride in bf16 elems (1536 + 8 pad)
#define IN_LD   200      // input row stride in bf16 elems (192 + 8 pad)
#define O_LD    904      // obuf row stride in f32 (896 + 8 pad)

typedef __attribute__((ext_vector_type(8))) short short8;
typedef __attribute__((ext_vector_type(4))) float f32x4;

#define MFMA_BF16(a,b,c) __builtin_amdgcn_mfma_f32_16x16x32_bf16((a),(b),(c),0,0,0)
#define TS 4096   // B elems between a wave's consecutive n-tiles (8 tiles * 512)

__device__ __forceinline__ unsigned short f2bf(float f) {
  unsigned u = __builtin_bit_cast(unsigned, f);
  u += 0x7fffu + ((u >> 16) & 1u);            // round-to-nearest-even
  return (unsigned short)(u >> 16);
}
__device__ __forceinline__ float wave_sum64(float v) {
  #pragma unroll
  for (int o = 32; o > 0; o >>= 1) v += __shfl_xor(v, o, 64);
  return v;
}
__device__ __forceinline__ float softplusf(float t) {
  return fmaxf(t, 0.f) + log1pf(expf(-fabsf(t)));
}

// ---------------------------------------------------------------------------
// Merged pack: all three weights in ONE launch.
//   [0,576)      w1 [1536][192]
//   [576,5184)   w2 [1536][1536]
//   [5184,7872)  w3 [896][1536]
// out[(kb*(N/16)+nb)*512 + lane*8 + j] = bf16( W[nb*16+(l&15)][kb*32+(l>>4)*8+j] )
// ---------------------------------------------------------------------------
__global__ __launch_bounds__(256) void pack_all(
    const float* __restrict__ w1, const float* __restrict__ w2,
    const float* __restrict__ w3,
    unsigned short* __restrict__ w1p, unsigned short* __restrict__ w2p,
    unsigned short* __restrict__ w3p) {
  const int wv = (blockIdx.x * 256 + threadIdx.x) >> 6;
  const int lane = threadIdx.x & 63;
  const float* W; unsigned short* out; int N, K, id;
  if (wv < 576)       { W = w1; out = w1p; N = WIDTH; K = IN1;   id = wv; }
  else if (wv < 5184) { W = w2; out = w2p; N = WIDTH; K = WIDTH; id = wv - 576; }
  else if (wv < 7872) { W = w3; out = w3p; N = ONC;   K = WIDTH; id = wv - 5184; }
  else return;
  const int nbt = N / 16;
  const int kb = id / nbt, nb = id - kb * nbt;
  const int n = nb * 16 + (lane & 15);
  const int k = kb * 32 + (lane >> 4) * 8;
  const float* src = W + (size_t)n * K + k;
  const float4 v0 = *(const float4*)src;
  const float4 v1 = *(const float4*)(src + 4);
  short8 o;
  o[0] = (short)f2bf(v0.x); o[1] = (short)f2bf(v0.y);
  o[2] = (short)f2bf(v0.z); o[3] = (short)f2bf(v0.w);
  o[4] = (short)f2bf(v1.x); o[5] = (short)f2bf(v1.y);
  o[6] = (short)f2bf(v1.z); o[7] = (short)f2bf(v1.w);
  *(short8*)(out + ((size_t)id * 64 + lane) * 8) = o;
}

// ---------------------------------------------------------------------------
// Depth-4 pipelined B-stream, trailing refills (R6-verified structure).
// ---------------------------------------------------------------------------
template<int RBT, int NTILE, int ASTR, int NKB>
__device__ __forceinline__ void stream4(
    const unsigned short* __restrict__ pB, size_t kstr,
    const unsigned short* hbase, int ald,
    f32x4* acc, int l15, int l4)
{
  const unsigned short* pA[RBT];
  #pragma unroll
  for (int rb = 0; rb < RBT; ++rb) pA[rb] = hbase + (size_t)(rb * 16 + l15) * ald + l4 * 8;

  short8 B0[NTILE], B1[NTILE], B2[NTILE], B3[NTILE];
  #pragma unroll
  for (int nb = 0; nb < NTILE; ++nb) B0[nb] = *(const short8*)(pB + nb * TS);
  pB += kstr;
  #pragma unroll
  for (int nb = 0; nb < NTILE; ++nb) B1[nb] = *(const short8*)(pB + nb * TS);
  pB += kstr;
  #pragma unroll
  for (int nb = 0; nb < NTILE; ++nb) B2[nb] = *(const short8*)(pB + nb * TS);
  pB += kstr;
  #pragma unroll
  for (int nb = 0; nb < NTILE; ++nb) B3[nb] = *(const short8*)(pB + nb * TS);
  pB += kstr;

  short8 aE[RBT], aO[RBT];
  #pragma unroll
  for (int rb = 0; rb < RBT; ++rb) aE[rb] = *(const short8*)(pA[rb]);

  #pragma unroll 1
  for (int it = 0; it < NKB / 4 - 1; ++it) {
    const int kb = it * 4;
    #pragma unroll
    for (int rb = 0; rb < RBT; ++rb) aO[rb] = *(const short8*)(pA[rb] + (kb + 1) * 32);
    __builtin_amdgcn_s_setprio(1);
    #pragma unroll
    for (int nb = 0; nb < NTILE; ++nb)
      #pragma unroll
      for (int rb = 0; rb < RBT; ++rb)
        acc[rb * ASTR + nb] = MFMA_BF16(aE[rb], B0[nb], acc[rb * ASTR + nb]);
    __builtin_amdgcn_s_setprio(0);
    #pragma unroll
    for (int nb = 0; nb < NTILE; ++nb) B0[nb] = *(const short8*)(pB + nb * TS);
    pB += kstr;

    #pragma unroll
    for (int rb = 0; rb < RBT; ++rb) aE[rb] = *(const short8*)(pA[rb] + (kb + 2) * 32);
    __builtin_amdgcn_s_setprio(1);
    #pragma unroll
    for (int nb = 0; nb < NTILE; ++nb)
      #pragma unroll
      for (int rb = 0; rb < RBT; ++rb)
        acc[rb * ASTR + nb] = MFMA_BF16(aO[rb], B1[nb], acc[rb * ASTR + nb]);
    __builtin_amdgcn_s_setprio(0);
    #pragma unroll
    for (int nb = 0; nb < NTILE; ++nb) B1[nb] = *(const short8*)(pB + nb * TS);
    pB += kstr;

    #pragma unroll
    for (int rb = 0; rb < RBT; ++rb) aO[rb] = *(const short8*)(pA[rb] + (kb + 3) * 32);
    __builtin_amdgcn_s_setprio(1);
    #pragma unroll
    for (int nb = 0; nb < NTILE; ++nb)
      #pragma unroll
      for (int rb = 0; rb < RBT; ++rb)
        acc[rb * ASTR + nb] = MFMA_BF16(aE[rb], B2[nb], acc[rb * ASTR + nb]);
    __builtin_amdgcn_s_setprio(0);
    #pragma unroll
    for (int nb = 0; nb < NTILE; ++nb) B2[nb] = *(const short8*)(pB + nb * TS);
    pB += kstr;

    #pragma unroll
    for (int rb = 0; rb < RBT; ++rb) aE[rb] = *(const short8*)(pA[rb] + (kb + 4) * 32);
    __builtin_amdgcn_s_setprio(1);
    #pragma unroll
    for (int nb = 0; nb < NTILE; ++nb)
      #pragma unroll
      for (int rb = 0; rb < RBT; ++rb)
        acc[rb * ASTR + nb] = MFMA_BF16(aO[rb], B3[nb], acc[rb * ASTR + nb]);
    __builtin_amdgcn_s_setprio(0);
    #pragma unroll
    for (int nb = 0; nb < NTILE; ++nb) B3[nb] = *(const short8*)(pB + nb * TS);
    pB += kstr;
  }
  {
    #pragma unroll
    for (int rb = 0; rb < RBT; ++rb) aO[rb] = *(const short8*)(pA[rb] + (NKB - 3) * 32);
    __builtin_amdgcn_s_setprio(1);
    #pragma unroll
    for (int nb = 0; nb < NTILE; ++nb)
      #pragma unroll
      for (int rb = 0; rb < RBT; ++rb)
        acc[rb * ASTR + nb] = MFMA_BF16(aE[rb], B0[nb], acc[rb * ASTR + nb]);
    #pragma unroll
    for (int rb = 0; rb < RBT; ++rb) aE[rb] = *(const short8*)(pA[rb] + (NKB - 2) * 32);
    #pragma unroll
    for (int nb = 0; nb < NTILE; ++nb)
      #pragma unroll
      for (int rb = 0; rb < RBT; ++rb)
        acc[rb * ASTR + nb] = MFMA_BF16(aO[rb], B1[nb], acc[rb * ASTR + nb]);
    #pragma unroll
    for (int rb = 0; rb < RBT; ++rb) aO[rb] = *(const short8*)(pA[rb] + (NKB - 1) * 32);
    #pragma unroll
    for (int nb = 0; nb < NTILE; ++nb)
      #pragma unroll
      for (int rb = 0; rb < RBT; ++rb)
        acc[rb * ASTR + nb] = MFMA_BF16(aE[rb], B2[nb], acc[rb * ASTR + nb]);
    #pragma unroll
    for (int nb = 0; nb < NTILE; ++nb)
      #pragma unroll
      for (int rb = 0; rb < RBT; ++rb)
        acc[rb * ASTR + nb] = MFMA_BF16(aO[rb], B3[nb], acc[rb * ASTR + nb]);
    __builtin_amdgcn_s_setprio(0);
  }
}

// ---------------------------------------------------------------------------
// Runtime-bound depth-2 stream for short AR tail segments (R6-verified).
// ---------------------------------------------------------------------------
template<int RBT, int NTILE, int ASTR>
__device__ __forceinline__ void stream_rt(
    const unsigned short* __restrict__ pB, size_t kstr,
    const unsigned short* hbase, int ald,
    f32x4* acc, int l15, int l4, int nkb)
{
  if (nkb <= 0) return;
  const unsigned short* pA[RBT];
  #pragma unroll
  for (int rb = 0; rb < RBT; ++rb) pA[rb] = hbase + (size_t)(rb * 16 + l15) * ald + l4 * 8;

  short8 bA[NTILE], bB[NTILE], av[RBT];
  #pragma unroll
  for (int nb = 0; nb < NTILE; ++nb) bA[nb] = *(const short8*)(pB + nb * TS);
  pB += kstr;
  int k = 0;
  #pragma unroll 1
  for (; k + 2 <= nkb; k += 2) {
    #pragma unroll
    for (int nb = 0; nb < NTILE; ++nb) bB[nb] = *(const short8*)(pB + nb * TS);
    pB += kstr;
    #pragma unroll
    for (int rb = 0; rb < RBT; ++rb) av[rb] = *(const short8*)(pA[rb] + k * 32);
    __builtin_amdgcn_s_setprio(1);
    #pragma unroll
    for (int nb = 0; nb < NTILE; ++nb)
      #pragma unroll
      for (int rb = 0; rb < RBT; ++rb)
        acc[rb * ASTR + nb] = MFMA_BF16(av[rb], bA[nb], acc[rb * ASTR + nb]);
    __builtin_amdgcn_s_setprio(0);
    if (k + 2 < nkb) {
      #pragma unroll
      for (int nb = 0; nb < NTILE; ++nb) bA[nb] = *(const short8*)(pB + nb * TS);
    }
    pB += kstr;
    #pragma unroll
    for (int rb = 0; rb < RBT; ++rb) av[rb] = *(const short8*)(pA[rb] + (k + 1) * 32);
    __builtin_amdgcn_s_setprio(1);
    #pragma unroll
    for (int nb = 0; nb < NTILE; ++nb)
      #pragma unroll
      for (int rb = 0; rb < RBT; ++rb)
        acc[rb * ASTR + nb] = MFMA_BF16(av[rb], bB[nb], acc[rb * ASTR + nb]);
    __builtin_amdgcn_s_setprio(0);
  }
  if (k < nkb) {
    #pragma unroll
    for (int rb = 0; rb < RBT; ++rb) av[rb] = *(const short8*)(pA[rb] + k * 32);
    #pragma unroll
    for (int nb = 0; nb < NTILE; ++nb)
      #pragma unroll
      for (int rb = 0; rb < RBT; ++rb)
        acc[rb * ASTR + nb] = MFMA_BF16(av[rb], bA[nb], acc[rb * ASTR + nb]);
  }
}

// ---------------------------------------------------------------------------
// bias + leaky + LayerNorm (wave w owns n-tiles {8a+w}).
// ---------------------------------------------------------------------------
template<int RBT>
__device__ __forceinline__ void act_ln(f32x4 (&acc)[RBT][12],
    const float* __restrict__ bias, const float* __restrict__ gam,
    const float* __restrict__ bet,
    unsigned short* hbuf, float* red, float* mstd,
    int t, int w, int l15, int l4)
{
  #pragma unroll
  for (int nb = 0; nb < 12; ++nb) {
    const float bb = bias[nb * 128 + w * 16 + l15];
    #pragma unroll
    for (int rb = 0; rb < RBT; ++rb)
      #pragma unroll
      for (int i = 0; i < 4; ++i) {
        float v = acc[rb][nb][i] + bb;
        acc[rb][nb][i] = v > 0.f ? v : 0.2f * v;
      }
  }
  #pragma unroll
  for (int rb = 0; rb < RBT; ++rb)
    #pragma unroll
    for (int i = 0; i < 4; ++i) {
      float ss = 0.f, qq = 0.f;
      #pragma unroll
      for (int nb = 0; nb < 12; ++nb) {
        const float v = acc[rb][nb][i];
        ss += v; qq += v * v;
      }
      #pragma unroll
      for (int o = 1; o < 16; o <<= 1) { ss += __shfl_xor(ss, o, 64); qq += __shfl_xor(qq, o, 64); }
      if (l15 == 0) {
        const int r = rb * 16 + l4 * 4 + i;
        red[w * 96 + r] = ss;
        red[w * 96 + 48 + r] = qq;
      }
    }
  __syncthreads();
  if (t < 16 * RBT) {
    float ss = 0.f, qq = 0.f;
    #pragma unroll
    for (int w8 = 0; w8 < 8; ++w8) { ss += red[w8 * 96 + t]; qq += red[w8 * 96 + 48 + t]; }
    const float m = ss * (1.f / (float)WIDTH);
    const float v = qq * (1.f / (float)WIDTH) - m * m;
    mstd[t] = m;
    mstd[48 + t] = rsqrtf(fmaxf(v, 0.f) + 1e-5f);
  }
  __syncthreads();
  float mm[RBT][4], rr[RBT][4];
  #pragma unroll
  for (int rb = 0; rb < RBT; ++rb)
    #pragma unroll
    for (int i = 0; i < 4; ++i) {
      const int r = rb * 16 + l4 * 4 + i;
      mm[rb][i] = mstd[r]; rr[rb][i] = mstd[48 + r];
    }
  #pragma unroll
  for (int rb = 0; rb < RBT; ++rb) {
    unsigned short* wp = hbuf + (size_t)(rb * 16 + l4 * 4) * H_LD + w * 16 + l15;
    #pragma unroll
    for (int nb = 0; nb < 12; ++nb) {
      const int col = nb * 128 + w * 16 + l15;
      const float gg = gam[col], ee = bet[col];
      #pragma unroll
      for (int i = 0; i < 4; ++i)
        wp[(size_t)i * H_LD + nb * 128] =
            f2bf((acc[rb][nb][i] - mm[rb][i]) * rr[rb][i] * gg + ee);
    }
  }
  __syncthreads();
}

// ---------------------------------------------------------------------------
// RQS spline for one (row, dim): o = 14 params [W0..4, H0..4, D0..3]
// ---------------------------------------------------------------------------
__device__ __forceinline__ void spline_eval(const float* __restrict__ o, float xv,
                                            float& zret, float& ladd) {
  const float Wv0 = o[0], Wv1 = o[1], Wv2 = o[2], Wv3 = o[3], Wv4 = o[4];
  const float Hv0 = o[5], Hv1 = o[6], Hv2 = o[7], Hv3 = o[8], Hv4 = o[9];
  const float Dv0 = o[10], Dv1 = o[11], Dv2 = o[12], Dv3 = o[13];

  float mw = fmaxf(fmaxf(fmaxf(Wv0, Wv1), fmaxf(Wv2, Wv3)), Wv4);
  float e0 = expf(Wv0 - mw), e1 = expf(Wv1 - mw), e2 = expf(Wv2 - mw),
        e3 = expf(Wv3 - mw), e4 = expf(Wv4 - mw);
  float inv = 0.995f / (e0 + e1 + e2 + e3 + e4);
  const float wd0 = 0.001f + e0 * inv, wd1 = 0.001f + e1 * inv,
              wd2 = 0.001f + e2 * inv, wd3 = 0.001f + e3 * inv;
  const float c1 = wd0, c2 = c1 + wd1, c3 = c2 + wd2, c4 = c3 + wd3;
  const float wi0 = c1, wi1 = c2 - c1, wi2 = c3 - c2, wi3 = c4 - c3, wi4 = 1.f - c4;

  float mh = fmaxf(fmaxf(fmaxf(Hv0, Hv1), fmaxf(Hv2, Hv3)), Hv4);
  float f0 = expf(Hv0 - mh), f1e = expf(Hv1 - mh), f2e = expf(Hv2 - mh),
        f3e = expf(Hv3 - mh), f4e = expf(Hv4 - mh);
  float invh = 0.995f / (f0 + f1e + f2e + f3e + f4e);
  const float hd0 = 0.001f + f0 * invh, hd1 = 0.001f + f1e * invh,
              hd2 = 0.001f + f2e * invh, hd3 = 0.001f + f3e * invh;
  const float g1c = hd0, g2c = g1c + hd1, g3c = g2c + hd2, g4c = g3c + hd3;
  const float hi0 = g1c, hi1 = g2c - g1c, hi2 = g3c - g2c, hi3 = g4c - g3c, hi4 = 1.f - g4c;

  const float dv1 = 0.001f + softplusf(Dv0), dv2 = 0.001f + softplusf(Dv1),
              dv3 = 0.001f + softplusf(Dv2), dv4 = 0.001f + softplusf(Dv3);

  const float s = 1.f / (1.f + expf(-xv));
  const int idx = (int)(s >= c1) + (int)(s >= c2) + (int)(s >= c3) + (int)(s >= c4);

  const float in_cw = idx == 0 ? 0.f : idx == 1 ? c1  : idx == 2 ? c2  : idx == 3 ? c3  : c4;
  const float in_w  = idx == 0 ? wi0 : idx == 1 ? wi1 : idx == 2 ? wi2 : idx == 3 ? wi3 : wi4;
  const float in_h  = idx == 0 ? hi0 : idx == 1 ? hi1 : idx == 2 ? hi2 : idx == 3 ? hi3 : hi4;
  const float in_ch = idx == 0 ? 0.f : idx == 1 ? g1c : idx == 2 ? g2c : idx == 3 ? g3c : g4c;
  const float d0    = idx == 0 ? 1.f : idx == 1 ? dv1 : idx == 2 ? dv2 : idx == 3 ? dv3 : dv4;
  const float d1    = idx == 0 ? dv1 : idx == 1 ? dv2 : idx == 2 ? dv3 : idx == 3 ? dv4 : 1.f;

  const float delta = in_h / in_w;
  const float th  = (s - in_cw) / in_w;
  const float omt = 1.f - th;
  const float t1  = th * omt;
  const float num = in_h * (delta * th * th + d0 * t1);
  const float den = delta + (d0 + d1 - 2.f * delta) * t1;
  float outv = in_ch + num / den;
  const float dnum = delta * delta * (d1 * th * th + 2.f * delta * t1 + d0 * omt * omt);
  const float lad_rqs = logf(dnum) - 2.f * logf(den);
  outv = outv * 0.999998f + 1e-6f;
  const float lo = logf(outv), l1m = logf(1.f - outv);
  const float logds = -softplusf(-xv) - softplusf(xv);
  zret = lo - l1m;
  ladd = logds + lad_rqs - lo - l1m;
}

// ---------------------------------------------------------------------------
// Fused kernel (R6-verified). Wave w owns n-tiles {8a+w}. Mask-aware K ranges:
//   GEMM1: feat tiles K=128 (4 kb); AR tiles +2 kb tail.
//   GEMM2: all tiles K=1024 (32 kb); AR tiles + runtime tail (<=16 kb).
//   GEMM3: all tiles 32 kb; two AR tail groups with per-group extents.
// Skipped ranges are exactly zero in the masked weights -> bitwise identical.
// ---------------------------------------------------------------------------
template<int RBT>
__global__ __launch_bounds__(NT, 2) void nsf_fused(
    const float* __restrict__ x, const float* __restrict__ feat,
    const unsigned short* __restrict__ w1p, const float* __restrict__ b1,
    const float* __restrict__ g1, const float* __restrict__ be1,
    const unsigned short* __restrict__ w2p, const float* __restrict__ b2,
    const float* __restrict__ g2, const float* __restrict__ be2,
    const unsigned short* __restrict__ w3p, const float* __restrict__ b3,
    float* __restrict__ zout, float* __restrict__ ladout, int rowbase)
{
  constexpr int BMT = 16 * RBT;
  __shared__ __align__(16) unsigned char smem[48 * H_LD * 2 + 768 * 4 + 96 * 4];
  unsigned short* hbuf = (unsigned short*)smem;
  float* red  = (float*)(smem + 48 * H_LD * 2);
  float* mstd = red + 768;

  const int t = threadIdx.x;
  const int lane = t & 63, w = t >> 6;
  const int l15 = lane & 15, l4 = lane >> 4;
  const int b0 = rowbase + blockIdx.x * BMT;

  // ---- stage concat([feat, x]) as bf16 ----
  for (int idx = t; idx < BMT * IN1; idx += NT) {
    const int r = idx / IN1, c = idx - r * IN1;
    const int row = b0 + r;
    const float v = (c < FEATD) ? feat[(size_t)row * FEATD + c]
                                : x[(size_t)row * DIMX + (c - FEATD)];
    hbuf[r * IN_LD + c] = f2bf(v);
  }
  __syncthreads();

  // ================= GEMM1: wave tiles {8a+w}; feat K=128, AR +2 kb ==========
  f32x4 acc[RBT][12];
  #pragma unroll
  for (int rb = 0; rb < RBT; ++rb)
    #pragma unroll
    for (int nb = 0; nb < 12; ++nb) acc[rb][nb] = (f32x4){0.f, 0.f, 0.f, 0.f};

  stream4<RBT, 6, 12, 4>(w1p + (size_t)w * 512 + lane * 8, (size_t)96 * 512,
                         hbuf, IN_LD, &acc[0][0], l15, l4);
  stream4<RBT, 6, 12, 4>(w1p + (size_t)(48 + w) * 512 + lane * 8, (size_t)96 * 512,
                         hbuf, IN_LD, &acc[0][6], l15, l4);
  stream_rt<RBT, 4, 12>(w1p + ((size_t)4 * 96 + 64 + w) * 512 + lane * 8, (size_t)96 * 512,
                        hbuf + 4 * 32, IN_LD, &acc[0][8], l15, l4, 2);
  act_ln<RBT>(acc, b1, g1, be1, hbuf, red, mstd, t, w, l15, l4);

  // ================= GEMM2: K=1024 dense + AR tail ===========================
  #pragma unroll
  for (int rb = 0; rb < RBT; ++rb)
    #pragma unroll
    for (int nb = 0; nb < 12; ++nb) acc[rb][nb] = (f32x4){0.f, 0.f, 0.f, 0.f};

  stream4<RBT, 6, 12, 32>(w2p + (size_t)w * 512 + lane * 8, (size_t)96 * 512,
                          hbuf, H_LD, &acc[0][0], l15, l4);
  stream4<RBT, 6, 12, 32>(w2p + (size_t)(48 + w) * 512 + lane * 8, (size_t)96 * 512,
                          hbuf, H_LD, &acc[0][6], l15, l4);
  stream_rt<RBT, 4, 12>(w2p + ((size_t)32 * 96 + 64 + w) * 512 + lane * 8, (size_t)96 * 512,
                        hbuf + 32 * 32, H_LD, &acc[0][8], l15, l4, (26 + w) >> 1);
  act_ln<RBT>(acc, b2, g2, be2, hbuf, red, mstd, t, w, l15, l4);

  // ================= GEMM3: 7 tiles {8a+w}; K=1024 dense + 2 AR tails ========
  f32x4 acc3[RBT][7];
  #pragma unroll
  for (int rb = 0; rb < RBT; ++rb)
    #pragma unroll
    for (int nb = 0; nb < 7; ++nb) acc3[rb][nb] = (f32x4){0.f, 0.f, 0.f, 0.f};

  stream4<RBT, 7, 7, 32>(w3p + (size_t)w * 512 + lane * 8, (size_t)56 * 512,
                         hbuf, H_LD, &acc3[0][0], l15, l4);
  {
    const int jmaxA = (16 * (24 + w) + 15) / 14;
    const int jmaxB = (16 * (48 + w) + 15) / 14;
    int nkbA = (8 * jmaxA + 8 + 31) >> 5; if (nkbA > 16) nkbA = 16;
    int nkbB = (8 * jmaxB + 8 + 31) >> 5; if (nkbB > 16) nkbB = 16;
    stream_rt<RBT, 4, 7>(w3p + ((size_t)32 * 56 + w) * 512 + lane * 8, (size_t)56 * 512,
                         hbuf + 32 * 32, H_LD, &acc3[0][0], l15, l4, nkbA);
    stream_rt<RBT, 3, 7>(w3p + ((size_t)32 * 56 + 32 + w) * 512 + lane * 8, (size_t)56 * 512,
                         hbuf + 32 * 32, H_LD, &acc3[0][4], l15, l4, nkbB);
  }
  __syncthreads();   // all hbuf A-reads done; obuf may alias hbuf

  // ================= spline via block-shared obuf ============================
  float* obuf = (float*)smem;    // [16][O_LD] f32
  #pragma unroll 1
  for (int rb = 0; rb < RBT; ++rb) {
    #pragma unroll
    for (int a = 0; a < 7; ++a) {
      const int col = (8 * a + w) * 16 + l15;
      const float bb = b3[col];
      #pragma unroll
      for (int i = 0; i < 4; ++i)
        obuf[(size_t)(l4 * 4 + i) * O_LD + col] = acc3[rb][a][i] + bb;
    }
    __syncthreads();
    #pragma unroll 1
    for (int rr = 0; rr < 2; ++rr) {
      const int row = 2 * w + rr;
      const int grow = b0 + rb * 16 + row;
      const float xv = x[(size_t)grow * DIMX + lane];
      float z, lad;
      spline_eval(&obuf[(size_t)row * O_LD + lane * 14], xv, z, lad);
      zout[(size_t)grow * DIMX + lane] = z;
      const float tot = wave_sum64(lad);
      if (lane == 0) ladout[grow] = tot;
    }
    __syncthreads();
  }
}

// ---------------------------------------------------------------------------
extern "C" void kernel_launch(void* const* d_in, const int* in_sizes, int n_in,
                              void* d_out, int out_size, void* d_ws, size_t ws_size,
                              hipStream_t stream) {
  const float* x   = (const float*)d_in[0];
  const float* feat= (const float*)d_in[1];
  const float* w1  = (const float*)d_in[2];   // [1536][192]  pre-masked
  const float* b1  = (const float*)d_in[3];
  const float* g1  = (const float*)d_in[4];
  const float* be1 = (const float*)d_in[5];
  const float* w2  = (const float*)d_in[6];   // [1536][1536] pre-masked
  const float* b2  = (const float*)d_in[7];
  const float* g2  = (const float*)d_in[8];
  const float* be2 = (const float*)d_in[9];
  const float* w3  = (const float*)d_in[10];  // [896][1536]  pre-masked
  const float* b3  = (const float*)d_in[11];
  // masks unused: weights arrive pre-masked (mask is 0/1, idempotent).

  unsigned short* w1p = (unsigned short*)d_ws;                 // 576 tiles
  unsigned short* w2p = w1p + (size_t)576 * 512;               // 4608 tiles
  unsigned short* w3p = w2p + (size_t)4608 * 512;              // 2688 tiles

  pack_all<<<1968, 256, 0, stream>>>(w1, w2, w3, w1p, w2p, w3p);

  float* zout   = (float*)d_out;
  float* ladout = zout + (size_t)BATCH * DIMX;
  // Exact-fill mixed grid: 512 x 48 rows + 256 x 32 rows = 32768 rows.
  nsf_fused<3><<<512, NT, 0, stream>>>(x, feat, w1p, b1, g1, be1,
                                       w2p, b2, g2, be2, w3p, b3,
                                       zout, ladout, 0);
  nsf_fused<2><<<256, NT, 0, stream>>>(x, feat, w1p, b1, g1, be1,
                                       w2p, b2, g2, be2, w3p, b3,
                                       zout, ladout, 24576);
}